// Round 3
// baseline (423.835 us; speedup 1.0000x reference)
//
#include <hip/hip_runtime.h>
#include <math.h>

#define B_ 16
#define D_ 256
#define T_ 4096
#define K_ 1024
#define N_ (B_*T_)        // 65536

typedef __attribute__((ext_vector_type(8))) short short8;
typedef __attribute__((ext_vector_type(8))) unsigned short ushort8;
typedef __attribute__((ext_vector_type(4))) float f32x4;

#define CAND_MAX 24
#define EPS1 1.0e-3f
#define EPS2 5.0e-4f

__device__ __forceinline__ unsigned short f2bf(float f) {
  unsigned u = __float_as_uint(f);
  u += 0x7fffu + ((u >> 16) & 1u);
  return (unsigned short)(u >> 16);
}

__device__ __forceinline__ void gl_lds16(const void* g, void* l) {
  __builtin_amdgcn_global_load_lds((const __attribute__((address_space(1))) unsigned int*)g,
                                   (__attribute__((address_space(3))) unsigned int*)l,
                                   16, 0, 0);
}

// ---------------- bf16 split of x with transpose: x[b][d][t] -> xh[n][d] ----------------
__global__ void k_split(const float* __restrict__ x, unsigned short* __restrict__ xh) {
  __shared__ float xs[64 * 65];
  const int b = blockIdx.y, t0 = blockIdx.x * 64;
  const int tid = threadIdx.x;
  const int r = tid >> 4, cf = tid & 15;
  for (int dc = 0; dc < D_; dc += 64) {
#pragma unroll
    for (int p = 0; p < 4; ++p) {
      const int dd = r + p * 16;
      float4 v = *(const float4*)(x + (size_t)b * D_ * T_ + (size_t)(dc + dd) * T_ + t0 + cf * 4);
      xs[(cf * 4 + 0) * 65 + dd] = v.x;
      xs[(cf * 4 + 1) * 65 + dd] = v.y;
      xs[(cf * 4 + 2) * 65 + dd] = v.z;
      xs[(cf * 4 + 3) * 65 + dd] = v.w;
    }
    __syncthreads();
    const int c = tid & 7, row2 = tid >> 3;   // c: 16B chunk over d, row2: 0..31
#pragma unroll
    for (int p = 0; p < 2; ++p) {
      const int tt = row2 + p * 32;
      ushort8 hv;
#pragma unroll
      for (int j = 0; j < 8; ++j) hv[j] = f2bf(xs[tt * 65 + c * 8 + j]);
      *(ushort8*)(xh + (size_t)(b * T_ + t0 + tt) * D_ + dc + c * 8) = hv;
    }
    __syncthreads();
  }
}

// ---------------- bf16 of w (no transpose): wh[k][d] ----------------
__global__ void k_wsplit(const float* __restrict__ w, unsigned short* __restrict__ wh) {
  const int i = blockIdx.x * 256 + threadIdx.x;
  if (i < K_ * D_) wh[i] = f2bf(w[i]);
}

// ---------------- wsq[k] in numpy pairwise order ----------------
__global__ void k_wsq(const float* __restrict__ w, float* __restrict__ wsq) {
#pragma clang fp contract(off)
  const int k = blockIdx.x * 256 + threadIdx.x;
  const float* row = w + (size_t)k * D_;
  float h[2];
#pragma unroll
  for (int half = 0; half < 2; ++half) {
    const float* a = row + half * 128;
    float r[8];
#pragma unroll
    for (int j = 0; j < 8; ++j) { float v = a[j]; r[j] = v * v; }
    for (int i = 8; i < 128; i += 8) {
#pragma unroll
      for (int j = 0; j < 8; ++j) { float v = a[i + j]; r[j] += v * v; }
    }
    h[half] = ((r[0] + r[1]) + (r[2] + r[3])) + ((r[4] + r[5]) + (r[6] + r[7]));
  }
  wsq[k] = h[0] + h[1];
}

// ---------------- xsq[n] in numpy pairwise order ----------------
__global__ void k_xsq(const float* __restrict__ x, float* __restrict__ xsq) {
#pragma clang fp contract(off)
  const int t = blockIdx.x * 256 + threadIdx.x;
  const int b = blockIdx.y;
  const float* p = x + (size_t)b * D_ * T_ + t;
  float h[2];
#pragma unroll
  for (int half = 0; half < 2; ++half) {
    const float* ph = p + (size_t)half * 128 * T_;
    float r[8];
#pragma unroll
    for (int j = 0; j < 8; ++j) { float v = ph[(size_t)j * T_]; r[j] = v * v; }
    for (int i = 8; i < 128; i += 8) {
#pragma unroll
      for (int j = 0; j < 8; ++j) { float v = ph[(size_t)(i + j) * T_]; r[j] += v * v; }
    }
    h[half] = ((r[0] + r[1]) + (r[2] + r[3])) + ((r[4] + r[5]) + (r[6] + r[7]));
  }
  xsq[(size_t)b * T_ + t] = h[0] + h[1];
}

// ---------------- MFMA bf16: persistent-X blocks, K streamed via dbuf LDS ----------------
// grid 256 blocks x 256 threads. Wave w owns tokens [n0 + w*64, +64); A-frags in registers.
// K processed as 16 chunks of 64 codes, W chunk double-buffered in LDS (2 x 32 KB).
__launch_bounds__(256, 1)
__global__ void k_mfma(const unsigned short* __restrict__ xh, const unsigned short* __restrict__ wh,
                       const float* __restrict__ xsq, const float* __restrict__ wsq,
                       int* __restrict__ cnt, int2* __restrict__ cand) {
  __shared__ unsigned short Wl[2][16384];   // 2 x 32 KB: [dg(8)][code(64)][slot(4)*8]
  const int tid = threadIdx.x;
  const int wave = tid >> 6, lane = tid & 63;
  const int col = lane & 15, quad = lane >> 4;
  const int n0 = blockIdx.x * 256;
  const int tok0 = n0 + wave * 64;

  // A fragments in registers: [dg][fm], one-time global read (32 MB total across grid)
  short8 A[8][4];
#pragma unroll
  for (int dg = 0; dg < 8; ++dg)
#pragma unroll
    for (int fm = 0; fm < 4; ++fm)
      A[dg][fm] = *(const short8*)(xh + (size_t)(tok0 + fm * 16 + col) * D_ + dg * 32 + quad * 8);

  float xq[4][4];
#pragma unroll
  for (int fm = 0; fm < 4; ++fm)
#pragma unroll
    for (int r = 0; r < 4; ++r)
      xq[fm][r] = xsq[tok0 + fm * 16 + quad * 4 + r];

  float runmin[4][4];
#pragma unroll
  for (int fm = 0; fm < 4; ++fm)
#pragma unroll
    for (int r = 0; r < 4; ++r) runmin[fm][r] = INFINITY;

  // staging: wave stages codes [kc*64 + wave*16, +16), all 8 dg, XOR-swizzled chunks
  const int srow = lane >> 2;                       // code within 16-group
  const int gq = (lane & 3) ^ ((lane >> 3) & 3);    // swizzled global d-chunk

#define STAGE(KC, HALF)                                                          \
  {                                                                              \
    const unsigned short* wsrc =                                                 \
        wh + (size_t)((KC) * 64 + wave * 16 + srow) * D_ + gq * 8;               \
    unsigned short* dstb = &Wl[HALF][wave * 512];                                \
    _Pragma("unroll")                                                            \
    for (int dg = 0; dg < 8; ++dg)                                               \
      gl_lds16(wsrc + dg * 32, dstb + dg * 2048);                                \
  }

  STAGE(0, 0)
  __syncthreads();

  for (int kc = 0; kc < 16; ++kc) {
    const int half = kc & 1;
    if (kc < 15) STAGE(kc + 1, half ^ 1)   // async prefetch, drained at loop-end barrier

    f32x4 acc[4][4] = {};
    const unsigned short* Wb = Wl[half];
#pragma unroll
    for (int dg = 0; dg < 8; ++dg) {
      short8 b[4];
#pragma unroll
      for (int fn = 0; fn < 4; ++fn)
        b[fn] = *(const short8*)(Wb + dg * 2048 + (fn * 16 + col) * 32 +
                                 (quad ^ ((col >> 1) & 3)) * 8);
#pragma unroll
      for (int fm = 0; fm < 4; ++fm)
#pragma unroll
        for (int fn = 0; fn < 4; ++fn)
          acc[fm][fn] = __builtin_amdgcn_mfma_f32_16x16x32_bf16(A[dg][fm], b[fn], acc[fm][fn], 0, 0, 0);
    }

    // epilogue: scores, running row-min in registers, rare candidate appends
    float wq[4];
#pragma unroll
    for (int fn = 0; fn < 4; ++fn) wq[fn] = wsq[kc * 64 + fn * 16 + col];

#pragma unroll
    for (int fm = 0; fm < 4; ++fm)
#pragma unroll
      for (int r = 0; r < 4; ++r) {
        float s[4];
        float v = INFINITY;
#pragma unroll
        for (int fn = 0; fn < 4; ++fn) {
          s[fn] = (xq[fm][r] + wq[fn]) - 2.0f * acc[fm][fn][r];
          v = fminf(v, s[fn]);
        }
        v = fminf(v, __shfl_xor(v, 1));
        v = fminf(v, __shfl_xor(v, 2));
        v = fminf(v, __shfl_xor(v, 4));
        v = fminf(v, __shfl_xor(v, 8));
        runmin[fm][r] = fminf(runmin[fm][r], v);
        const float thr = runmin[fm][r] + EPS1;
        const int n = tok0 + fm * 16 + quad * 4 + r;
#pragma unroll
        for (int fn = 0; fn < 4; ++fn) {
          if (s[fn] <= thr) {
            const int p = atomicAdd(&cnt[n], 1);
            if (p < CAND_MAX)
              cand[(size_t)n * CAND_MAX + p] =
                  make_int2(kc * 64 + fn * 16 + col, __float_as_int(s[fn]));
          }
        }
      }
    __syncthreads();   // drains prefetch (vmcnt) + guards buffer reuse
  }
}

// ---------------- exact rescore: replicate round-1 fp32 fmaf chain bitwise ----------------
__global__ void k_rescore(const float* __restrict__ x, const float* __restrict__ w,
                          const float* __restrict__ xsq, const float* __restrict__ wsq,
                          const int* __restrict__ cnt, const int2* __restrict__ cand,
                          int* __restrict__ final_idx) {
  __shared__ float xrow[64 * 257];
  __shared__ unsigned int sbits[64];
  __shared__ unsigned long long fin[64];
  const int blk = blockIdx.x;
  const int b = (blk * 64) >> 12, t0 = (blk * 64) & (T_ - 1);
  const int tid = threadIdx.x;
  const int r = tid >> 4, cf = tid & 15;
  if (tid < 64) { sbits[tid] = 0xffffffffu; fin[tid] = ~0ULL; }
  for (int dc = 0; dc < D_; dc += 64) {
#pragma unroll
    for (int p = 0; p < 4; ++p) {
      const int dd = r + p * 16;
      float4 v = *(const float4*)(x + (size_t)b * D_ * T_ + (size_t)(dc + dd) * T_ + t0 + cf * 4);
      xrow[(cf * 4 + 0) * 257 + dc + dd] = v.x;
      xrow[(cf * 4 + 1) * 257 + dc + dd] = v.y;
      xrow[(cf * 4 + 2) * 257 + dc + dd] = v.z;
      xrow[(cf * 4 + 3) * 257 + dc + dd] = v.w;
    }
  }
  __syncthreads();
  const int row = tid & 63;
  const int n = blk * 64 + row;
  const int c0 = tid >> 6;
  const int nc = min(cnt[n], CAND_MAX);
  for (int c = c0; c < nc; c += 4)
    atomicMin(&sbits[row], (unsigned)cand[(size_t)n * CAND_MAX + c].y);
  __syncthreads();
  const float th = __uint_as_float(sbits[row]) + EPS2;
  const float xq = xsq[n];
  for (int c = c0; c < nc; c += 4) {
    const int2 e = cand[(size_t)n * CAND_MAX + c];
    if (__int_as_float(e.y) <= th) {
      const float* wr = w + (size_t)e.x * D_;
      float acc = 0.f;
#pragma unroll 8
      for (int d = 0; d < D_; ++d) acc = fmaf(xrow[row * 257 + d], wr[d], acc);
      const float s = (xq + wsq[e.x]) - 2.0f * acc;   // bitwise == round-1 score
      atomicMin(&fin[row], ((unsigned long long)__float_as_uint(s) << 32) | (unsigned)e.x);
    }
  }
  __syncthreads();
  if (tid < 64) final_idx[blk * 64 + tid] = (int)(fin[tid] & 0xffffffffULL);
}

// ---------------- gather + transpose + loss partials + counts + idx ----------------
__global__ void k_emit(const float* __restrict__ x, const float* __restrict__ w,
                       const int* __restrict__ fidx,
                       float* __restrict__ out0, float* __restrict__ out_idx,
                       int* __restrict__ counts, float* __restrict__ sumsq) {
  __shared__ float xs[64 * 65];
  __shared__ int sidx[64];
  __shared__ float sred[4];
  const int b = blockIdx.y, t0 = blockIdx.x * 64;
  const int tid = threadIdx.x;

  if (tid < 64) {
    const int n = b * T_ + t0 + tid;
    const int idx = fidx[n];
    sidx[tid] = idx;
    out_idx[n] = (float)idx;
    atomicAdd(&counts[idx], 1);
  }
  __syncthreads();

  const int r = tid >> 4;
  const int c = tid & 15;
  float lsum = 0.f;
  for (int dc = 0; dc < D_; dc += 64) {
#pragma unroll
    for (int p = 0; p < 4; ++p) {
      const int dd = r + p * 16;
      float4 v = *(const float4*)(x + (size_t)b * D_ * T_ + (size_t)(dc + dd) * T_ + t0 + c * 4);
      xs[(c * 4 + 0) * 65 + dd] = v.x;
      xs[(c * 4 + 1) * 65 + dd] = v.y;
      xs[(c * 4 + 2) * 65 + dd] = v.z;
      xs[(c * 4 + 3) * 65 + dd] = v.w;
    }
    __syncthreads();
    const int dx = tid & 15;
    const int tg = tid >> 4;
#pragma unroll
    for (int q = 0; q < 4; ++q) {
      const int t = q * 16 + tg;
      const int idx = sidx[t];
      const float4 wv = *(const float4*)(w + (size_t)idx * D_ + dc + dx * 4);
      const float x0 = xs[t * 65 + dx * 4 + 0];
      const float x1 = xs[t * 65 + dx * 4 + 1];
      const float x2 = xs[t * 65 + dx * 4 + 2];
      const float x3 = xs[t * 65 + dx * 4 + 3];
      const float d0 = wv.x - x0, d1 = wv.y - x1, d2 = wv.z - x2, d3 = wv.w - x3;
      float4 ov = make_float4(x0 + d0, x1 + d1, x2 + d2, x3 + d3);
      *(float4*)(out0 + (size_t)(b * T_ + t0 + t) * D_ + dc + dx * 4) = ov;
      lsum += d0 * d0 + d1 * d1 + d2 * d2 + d3 * d3;
    }
    __syncthreads();
  }
  for (int off = 32; off; off >>= 1) lsum += __shfl_down(lsum, off);
  if ((tid & 63) == 0) sred[tid >> 6] = lsum;
  __syncthreads();
  if (tid == 0) atomicAdd(sumsq, sred[0] + sred[1] + sred[2] + sred[3]);
}

// ---------------- loss + perplexity ----------------
__global__ void k_final(const int* __restrict__ counts, const float* __restrict__ sumsq,
                        float* __restrict__ out_scalars) {
  __shared__ float sred[4];
  const int tid = threadIdx.x;
  float s = 0.f;
  for (int k = tid; k < K_; k += 256) {
    const float p = (float)counts[k] / (float)N_;
    s += p * logf(p + 1e-10f);
  }
  for (int off = 32; off; off >>= 1) s += __shfl_down(s, off);
  if ((tid & 63) == 0) sred[tid >> 6] = s;
  __syncthreads();
  if (tid == 0) {
    const float ent = sred[0] + sred[1] + sred[2] + sred[3];
    const float m = sumsq[0] / 16777216.0f;
    out_scalars[0] = m + 0.25f * m;
    out_scalars[1] = expf(-ent);
  }
}

// ================= round-1 fallback path (used only if ws too small) =================
__global__ void k_wt(const float* __restrict__ w, float* __restrict__ wt) {
  __shared__ float tile[64][65];
  const int k0 = blockIdx.x * 64, d0 = blockIdx.y * 64;
  const int c = threadIdx.x & 15, r = threadIdx.x >> 4;
#pragma unroll
  for (int p = 0; p < 4; ++p) {
    const int kk = r + p * 16;
    float4 v = *(const float4*)(w + (size_t)(k0 + kk) * D_ + d0 + c * 4);
    tile[kk][c * 4 + 0] = v.x; tile[kk][c * 4 + 1] = v.y;
    tile[kk][c * 4 + 2] = v.z; tile[kk][c * 4 + 3] = v.w;
  }
  __syncthreads();
#pragma unroll
  for (int p = 0; p < 4; ++p) {
    const int dd = r + p * 16;
    float4 v = make_float4(tile[c * 4 + 0][dd], tile[c * 4 + 1][dd],
                           tile[c * 4 + 2][dd], tile[c * 4 + 3][dd]);
    *(float4*)(wt + (size_t)(d0 + dd) * K_ + k0 + c * 4) = v;
  }
}

__launch_bounds__(256, 4)
__global__ void k_argmin(const float* __restrict__ x, const float* __restrict__ wt,
                         const float* __restrict__ xsq, const float* __restrict__ wsq,
                         unsigned long long* __restrict__ packed) {
  extern __shared__ char smem[];
  float* Xs = (float*)smem;
  float* Ws = (float*)(smem + 32 * 128 * sizeof(float));
  const int tid = threadIdx.x;
  const int tx = tid & 15, ty = tid >> 4;
  const int n0 = blockIdx.x * 128, k0 = blockIdx.y * 128;
  const int b = n0 >> 12, t0 = n0 & (T_ - 1);
  const float* xbase = x + (size_t)b * D_ * T_ + t0;
  const float* wbase = wt + k0;
  float acc[8][8];
#pragma unroll
  for (int i = 0; i < 8; ++i)
#pragma unroll
    for (int j = 0; j < 8; ++j) acc[i][j] = 0.f;
  const int sr = tid >> 5, sc = tid & 31;
  for (int dc = 0; dc < D_; dc += 32) {
#pragma unroll
    for (int p = 0; p < 4; ++p) {
      const int rr = sr + p * 8;
      const float4 xv = *(const float4*)(xbase + (size_t)(dc + rr) * T_ + sc * 4);
      *(float4*)(Xs + rr * 128 + sc * 4) = xv;
      const float4 wv = *(const float4*)(wbase + (size_t)(dc + rr) * K_ + sc * 4);
      *(float4*)(Ws + rr * 128 + sc * 4) = wv;
    }
    __syncthreads();
#pragma unroll 4
    for (int d = 0; d < 32; ++d) {
      const float4 xa = *(const float4*)(Xs + d * 128 + tx * 8);
      const float4 xb = *(const float4*)(Xs + d * 128 + tx * 8 + 4);
      const float4 wa = *(const float4*)(Ws + d * 128 + ty * 8);
      const float4 wb = *(const float4*)(Ws + d * 128 + ty * 8 + 4);
      const float xr[8] = {xa.x, xa.y, xa.z, xa.w, xb.x, xb.y, xb.z, xb.w};
      const float wr[8] = {wa.x, wa.y, wa.z, wa.w, wb.x, wb.y, wb.z, wb.w};
#pragma unroll
      for (int i = 0; i < 8; ++i)
#pragma unroll
        for (int j = 0; j < 8; ++j)
          acc[i][j] = fmaf(xr[i], wr[j], acc[i][j]);
    }
    __syncthreads();
  }
  float xq[8];
#pragma unroll
  for (int i = 0; i < 8; ++i) xq[i] = xsq[n0 + tx * 8 + i];
  float best[8]; int bidx[8];
#pragma unroll
  for (int i = 0; i < 8; ++i) { best[i] = INFINITY; bidx[i] = 0; }
#pragma unroll
  for (int j = 0; j < 8; ++j) {
    const int kk = k0 + ty * 8 + j;
    const float wq = wsq[kk];
#pragma unroll
    for (int i = 0; i < 8; ++i) {
      const float s = (xq[i] + wq) - 2.0f * acc[i][j];
      if (s < best[i]) { best[i] = s; bidx[i] = kk; }
    }
  }
  float* rv = (float*)smem;
  int* ri = (int*)(smem + 16 * 128 * sizeof(float));
#pragma unroll
  for (int i = 0; i < 8; ++i) {
    rv[ty * 128 + tx * 8 + i] = best[i];
    ri[ty * 128 + tx * 8 + i] = bidx[i];
  }
  __syncthreads();
  if (tid < 128) {
    float bv = rv[tid]; int bi = ri[tid];
#pragma unroll
    for (int u = 1; u < 16; ++u) {
      const float v = rv[u * 128 + tid];
      const int ii = ri[u * 128 + tid];
      if (v < bv || (v == bv && ii < bi)) { bv = v; bi = ii; }
    }
    const unsigned long long pk =
        ((unsigned long long)__float_as_uint(bv) << 32) | (unsigned int)bi;
    atomicMin(packed + n0 + tid, pk);
  }
}

__global__ void k_unpack(const unsigned long long* __restrict__ p, int* __restrict__ fi) {
  const int i = blockIdx.x * 256 + threadIdx.x;
  fi[i] = (int)(p[i] & 0xffffffffULL);
}

// =====================================================================================
extern "C" void kernel_launch(void* const* d_in, const int* in_sizes, int n_in,
                              void* d_out, int out_size, void* d_ws, size_t ws_size,
                              hipStream_t stream) {
  const float* x = (const float*)d_in[0];   // [16,256,4096]
  const float* w = (const float*)d_in[1];   // [1024,256]
  float* out = (float*)d_out;
  float* out0 = out;                    // [B,T,D]
  float* out_scalars = out + 16777216;  // loss, perplexity
  float* out_idx = out + 16777218;      // [N,1] as float

  char* ws = (char*)d_ws;
  const size_t NEED = 48u * 1024u * 1024u;

  if (ws_size >= NEED) {
    // ---- MFMA path ----
    unsigned short* xh = (unsigned short*)ws;                       // 32 MB
    unsigned short* wh = (unsigned short*)(ws + 33554432);          // 512 KB
    float* xsq = (float*)(ws + 34078720);                           // 256 KB
    float* wsq = (float*)(ws + 34340864);                           // 4 KB
    int* cnt = (int*)(ws + 34344960);                               // 256 KB
    int2* cand = (int2*)(ws + 34607104);                            // 12 MB
    int* final_idx = (int*)(ws + 47190016);                         // 256 KB
    int* counts = (int*)(ws + 47452160);                            // 4 KB
    float* sumsq = (float*)(ws + 47456256);

    hipMemsetAsync(cnt, 0, 262144, stream);
    hipMemsetAsync(counts, 0, 4096 + 256, stream);   // counts + sumsq

    k_split<<<dim3(T_ / 64, B_), dim3(256), 0, stream>>>(x, xh);
    k_wsplit<<<dim3((K_ * D_) / 256), dim3(256), 0, stream>>>(w, wh);
    k_wsq<<<dim3(K_ / 256), dim3(256), 0, stream>>>(w, wsq);
    k_xsq<<<dim3(T_ / 256, B_), dim3(256), 0, stream>>>(x, xsq);
    k_mfma<<<dim3(N_ / 256), dim3(256), 0, stream>>>(xh, wh, xsq, wsq, cnt, cand);
    k_rescore<<<dim3(N_ / 64), dim3(256), 0, stream>>>(x, w, xsq, wsq, cnt, cand, final_idx);
    k_emit<<<dim3(T_ / 64, B_), dim3(256), 0, stream>>>(x, w, final_idx, out0, out_idx, counts, sumsq);
    k_final<<<1, 256, 0, stream>>>(counts, sumsq, out_scalars);
  } else {
    // ---- round-1 fallback path ----
    unsigned long long* packed = (unsigned long long*)ws;            // 512 KB
    int* counts = (int*)(ws + 524288);                               // 4 KB
    float* sumsq = (float*)(ws + 528384);
    float* wsq = (float*)(ws + 528640);                              // 4 KB
    float* xsq = (float*)(ws + 532736);                              // 256 KB
    float* wt = (float*)(ws + 794880);                               // 1 MB
    int* final_idx = (int*)(ws + 1843200);                           // 256 KB

    hipMemsetAsync(packed, 0xFF, 524288, stream);
    hipMemsetAsync(counts, 0, 4096 + 256, stream);

    k_wt<<<dim3(K_ / 64, D_ / 64), dim3(256), 0, stream>>>(w, wt);
    k_wsq<<<dim3(K_ / 256), dim3(256), 0, stream>>>(w, wsq);
    k_xsq<<<dim3(T_ / 256, B_), dim3(256), 0, stream>>>(x, xsq);
    k_argmin<<<dim3(N_ / 128, K_ / 128), dim3(256), 32 * 1024, stream>>>(x, wt, xsq, wsq, packed);
    k_unpack<<<dim3(N_ / 256), dim3(256), 0, stream>>>(packed, final_idx);
    k_emit<<<dim3(T_ / 64, B_), dim3(256), 0, stream>>>(x, w, final_idx, out0, out_idx, counts, sumsq);
    k_final<<<1, 256, 0, stream>>>(counts, sumsq, out_scalars);
  }
}

// Round 4
// 323.999 us; speedup vs baseline: 1.3081x; 1.3081x over previous
//
#include <hip/hip_runtime.h>
#include <math.h>

#define B_ 16
#define D_ 256
#define T_ 4096
#define K_ 1024
#define N_ (B_*T_)        // 65536

typedef __attribute__((ext_vector_type(8))) short short8;
typedef __attribute__((ext_vector_type(8))) unsigned short ushort8;
typedef __attribute__((ext_vector_type(4))) float f32x4;

#define CAND_MAX 24
#define EPS1 1.0e-3f
#define EPS2 5.0e-4f

__device__ __forceinline__ unsigned short f2bf(float f) {
  unsigned u = __float_as_uint(f);
  u += 0x7fffu + ((u >> 16) & 1u);
  return (unsigned short)(u >> 16);
}

__device__ __forceinline__ void gl_lds16(const void* g, void* l) {
  __builtin_amdgcn_global_load_lds((const __attribute__((address_space(1))) unsigned int*)g,
                                   (__attribute__((address_space(3))) unsigned int*)l,
                                   16, 0, 0);
}

// ---------------- fused: bf16 split of x (transpose) + xsq in numpy pairwise order ----------
// grid (T/64, B), block 256.
__global__ void k_prep(const float* __restrict__ x, unsigned short* __restrict__ xh,
                       float* __restrict__ xsq) {
#pragma clang fp contract(off)
  __shared__ float xs[64 * 65];
  __shared__ float part[4][64][2];
  const int b = blockIdx.y, t0 = blockIdx.x * 64;
  const int tid = threadIdx.x;
  const int r = tid >> 4, cf = tid & 15;
  const int tok = tid & 63, cj = tid >> 6;   // 4 partial-threads per token: j = 2cj, 2cj+1
  float rr0[2] = {0.f, 0.f}, rr1[2] = {0.f, 0.f};
  for (int dc = 0; dc < D_; dc += 64) {
#pragma unroll
    for (int p = 0; p < 4; ++p) {
      const int dd = r + p * 16;
      float4 v = *(const float4*)(x + (size_t)b * D_ * T_ + (size_t)(dc + dd) * T_ + t0 + cf * 4);
      xs[(cf * 4 + 0) * 65 + dd] = v.x;
      xs[(cf * 4 + 1) * 65 + dd] = v.y;
      xs[(cf * 4 + 2) * 65 + dd] = v.z;
      xs[(cf * 4 + 3) * 65 + dd] = v.w;
    }
    __syncthreads();
    // bf16 conversion out
    {
      const int c = tid & 7, row2 = tid >> 3;
#pragma unroll
      for (int p = 0; p < 2; ++p) {
        const int tt = row2 + p * 32;
        ushort8 hv;
#pragma unroll
        for (int j = 0; j < 8; ++j) hv[j] = f2bf(xs[tt * 65 + c * 8 + j]);
        *(ushort8*)(xh + (size_t)(b * T_ + t0 + tt) * D_ + dc + c * 8) = hv;
      }
    }
    // xsq partials, np order: r[j] += v[8m+j]^2, m ascending; this chunk is one half-chunk
    {
      const int half = dc >> 7;
#pragma unroll
      for (int m = 0; m < 8; ++m) {
        const float v0 = xs[tok * 65 + m * 8 + 2 * cj];
        const float v1 = xs[tok * 65 + m * 8 + 2 * cj + 1];
        rr0[half] += v0 * v0;
        rr1[half] += v1 * v1;
      }
    }
    __syncthreads();
  }
  part[cj][tok][0] = rr0[0] + rr1[0];   // = r[2cj] + r[2cj+1], half 0
  part[cj][tok][1] = rr0[1] + rr1[1];
  __syncthreads();
  if (tid < 64) {
    const float h0 = (part[0][tid][0] + part[1][tid][0]) + (part[2][tid][0] + part[3][tid][0]);
    const float h1 = (part[0][tid][1] + part[1][tid][1]) + (part[2][tid][1] + part[3][tid][1]);
    xsq[(size_t)b * T_ + t0 + tid] = h0 + h1;
  }
}

// ---------------- bf16 of w (no transpose): wh[k][d] ----------------
__global__ void k_wsplit(const float* __restrict__ w, unsigned short* __restrict__ wh) {
  const int i = blockIdx.x * 256 + threadIdx.x;
  if (i < K_ * D_) wh[i] = f2bf(w[i]);
}

// ---------------- wsq[k] in numpy pairwise order ----------------
__global__ void k_wsq(const float* __restrict__ w, float* __restrict__ wsq) {
#pragma clang fp contract(off)
  const int k = blockIdx.x * 256 + threadIdx.x;
  const float* row = w + (size_t)k * D_;
  float h[2];
#pragma unroll
  for (int half = 0; half < 2; ++half) {
    const float* a = row + half * 128;
    float r[8];
#pragma unroll
    for (int j = 0; j < 8; ++j) { float v = a[j]; r[j] = v * v; }
    for (int i = 8; i < 128; i += 8) {
#pragma unroll
      for (int j = 0; j < 8; ++j) { float v = a[i + j]; r[j] += v * v; }
    }
    h[half] = ((r[0] + r[1]) + (r[2] + r[3])) + ((r[4] + r[5]) + (r[6] + r[7]));
  }
  wsq[k] = h[0] + h[1];
}

// ---------------- xsq (fallback path only) ----------------
__global__ void k_xsq(const float* __restrict__ x, float* __restrict__ xsq) {
#pragma clang fp contract(off)
  const int t = blockIdx.x * 256 + threadIdx.x;
  const int b = blockIdx.y;
  const float* p = x + (size_t)b * D_ * T_ + t;
  float h[2];
#pragma unroll
  for (int half = 0; half < 2; ++half) {
    const float* ph = p + (size_t)half * 128 * T_;
    float r[8];
#pragma unroll
    for (int j = 0; j < 8; ++j) { float v = ph[(size_t)j * T_]; r[j] = v * v; }
    for (int i = 8; i < 128; i += 8) {
#pragma unroll
      for (int j = 0; j < 8; ++j) { float v = ph[(size_t)(i + j) * T_]; r[j] += v * v; }
    }
    h[half] = ((r[0] + r[1]) + (r[2] + r[3])) + ((r[4] + r[5]) + (r[6] + r[7]));
  }
  xsq[(size_t)b * T_ + t] = h[0] + h[1];
}

// ---------------- MFMA bf16: persistent-X waves, K-half per block, two passes ----------------
// grid (N/256, 2), block 256 (4 waves). Wave owns 64 tokens; A-frags in registers.
// Pass 1: MFMA + register-only running min. Butterfly once. Pass 2: recompute + emit candidates.
__launch_bounds__(256, 2)
__global__ void k_mfma(const unsigned short* __restrict__ xh, const unsigned short* __restrict__ wh,
                       const float* __restrict__ xsq, const float* __restrict__ wsq,
                       int* __restrict__ cnt, int2* __restrict__ cand) {
  __shared__ unsigned short Wl[2][16384];   // 2 x 32 KB: [dg(8)][code(64)][8-elem chunk(4)]
  const int tid = threadIdx.x;
  const int wave = tid >> 6, lane = tid & 63;
  const int col = lane & 15, quad = lane >> 4;
  const int n0 = blockIdx.x * 256;
  const int kbase = blockIdx.y * 512;       // k-half
  const int tok0 = n0 + wave * 64;

  // A fragments in registers: [dg][fm]
  short8 A[8][4];
#pragma unroll
  for (int dg = 0; dg < 8; ++dg)
#pragma unroll
    for (int fm = 0; fm < 4; ++fm)
      A[dg][fm] = *(const short8*)(xh + (size_t)(tok0 + fm * 16 + col) * D_ + dg * 32 + quad * 8);

  float xq[4][4];
#pragma unroll
  for (int fm = 0; fm < 4; ++fm)
#pragma unroll
    for (int r = 0; r < 4; ++r)
      xq[fm][r] = xsq[tok0 + fm * 16 + quad * 4 + r];

  const int srow = lane >> 2;
  const int gq = (lane & 3) ^ ((lane >> 3) & 3);
  const unsigned short* wsrc0 = wh + (size_t)(kbase + wave * 16 + srow) * D_ + gq * 8;

#define STAGE(KC, HALF)                                                     \
  {                                                                         \
    const unsigned short* wsrc = wsrc0 + (size_t)(KC) * 64 * D_;            \
    unsigned short* dstb = &Wl[HALF][wave * 512];                           \
    _Pragma("unroll")                                                       \
    for (int dg = 0; dg < 8; ++dg)                                          \
      gl_lds16(wsrc + dg * 32, dstb + dg * 2048);                           \
  }

  float minl[4][4];
#pragma unroll
  for (int fm = 0; fm < 4; ++fm)
#pragma unroll
    for (int r = 0; r < 4; ++r) minl[fm][r] = INFINITY;

  // ---------- pass 1: min only ----------
  STAGE(0, 0)
  __syncthreads();
  for (int kc = 0; kc < 8; ++kc) {
    const int half = kc & 1;
    if (kc < 7) STAGE(kc + 1, half ^ 1)
    f32x4 acc[4][4] = {};
    const unsigned short* Wb = Wl[half];
#pragma unroll
    for (int dg = 0; dg < 8; ++dg) {
      short8 bfr[4];
#pragma unroll
      for (int fn = 0; fn < 4; ++fn)
        bfr[fn] = *(const short8*)(Wb + dg * 2048 + (fn * 16 + col) * 32 +
                                   (quad ^ ((col >> 1) & 3)) * 8);
#pragma unroll
      for (int fm = 0; fm < 4; ++fm)
#pragma unroll
        for (int fn = 0; fn < 4; ++fn)
          acc[fm][fn] = __builtin_amdgcn_mfma_f32_16x16x32_bf16(A[dg][fm], bfr[fn], acc[fm][fn], 0, 0, 0);
    }
    float wq[4];
#pragma unroll
    for (int fn = 0; fn < 4; ++fn) wq[fn] = wsq[kbase + kc * 64 + fn * 16 + col];
#pragma unroll
    for (int fm = 0; fm < 4; ++fm)
#pragma unroll
      for (int r = 0; r < 4; ++r)
#pragma unroll
        for (int fn = 0; fn < 4; ++fn) {
          const float s = (xq[fm][r] + wq[fn]) - 2.0f * acc[fm][fn][r];
          minl[fm][r] = fminf(minl[fm][r], s);
        }
    __syncthreads();
  }

  // one butterfly per row: min across the 16 lanes of each quad
  float rowmin[4][4];
#pragma unroll
  for (int fm = 0; fm < 4; ++fm)
#pragma unroll
    for (int r = 0; r < 4; ++r) {
      float v = minl[fm][r];
      v = fminf(v, __shfl_xor(v, 1));
      v = fminf(v, __shfl_xor(v, 2));
      v = fminf(v, __shfl_xor(v, 4));
      v = fminf(v, __shfl_xor(v, 8));
      rowmin[fm][r] = v;
    }

  // ---------- pass 2: recompute (bitwise-same) + emit candidates ----------
  STAGE(0, 0)
  __syncthreads();
  for (int kc = 0; kc < 8; ++kc) {
    const int half = kc & 1;
    if (kc < 7) STAGE(kc + 1, half ^ 1)
    f32x4 acc[4][4] = {};
    const unsigned short* Wb = Wl[half];
#pragma unroll
    for (int dg = 0; dg < 8; ++dg) {
      short8 bfr[4];
#pragma unroll
      for (int fn = 0; fn < 4; ++fn)
        bfr[fn] = *(const short8*)(Wb + dg * 2048 + (fn * 16 + col) * 32 +
                                   (quad ^ ((col >> 1) & 3)) * 8);
#pragma unroll
      for (int fm = 0; fm < 4; ++fm)
#pragma unroll
        for (int fn = 0; fn < 4; ++fn)
          acc[fm][fn] = __builtin_amdgcn_mfma_f32_16x16x32_bf16(A[dg][fm], bfr[fn], acc[fm][fn], 0, 0, 0);
    }
    float wq[4];
#pragma unroll
    for (int fn = 0; fn < 4; ++fn) wq[fn] = wsq[kbase + kc * 64 + fn * 16 + col];
#pragma unroll
    for (int fm = 0; fm < 4; ++fm)
#pragma unroll
      for (int r = 0; r < 4; ++r) {
        const float thr = rowmin[fm][r] + EPS1;
        const int n = tok0 + fm * 16 + quad * 4 + r;
#pragma unroll
        for (int fn = 0; fn < 4; ++fn) {
          const float s = (xq[fm][r] + wq[fn]) - 2.0f * acc[fm][fn][r];
          if (s <= thr) {
            const int p = atomicAdd(&cnt[n], 1);
            if (p < CAND_MAX)
              cand[(size_t)n * CAND_MAX + p] =
                  make_int2(kbase + kc * 64 + fn * 16 + col, __float_as_int(s));
          }
        }
      }
    __syncthreads();
  }
#undef STAGE
}

// ---------------- fused: exact rescore + gather/transpose emit + loss/counts ----------------
// grid (N/64), block 256. X staged once, used for both rescore fmaf chain and output write.
__global__ void k_resc_emit(const float* __restrict__ x, const float* __restrict__ w,
                            const float* __restrict__ xsq, const float* __restrict__ wsq,
                            const int* __restrict__ cnt, const int2* __restrict__ cand,
                            float* __restrict__ out0, float* __restrict__ out_idx,
                            int* __restrict__ counts, float* __restrict__ sumsq) {
  __shared__ float xrow[64 * 257];
  __shared__ unsigned int sbits[64];
  __shared__ unsigned long long fin[64];
  __shared__ int sidx[64];
  __shared__ float sred[4];
  const int blk = blockIdx.x;
  const int b = (blk * 64) >> 12, t0 = (blk * 64) & (T_ - 1);
  const int tid = threadIdx.x;
  const int r = tid >> 4, cf = tid & 15;
  if (tid < 64) { sbits[tid] = 0xffffffffu; fin[tid] = ~0ULL; }
  for (int dc = 0; dc < D_; dc += 64) {
#pragma unroll
    for (int p = 0; p < 4; ++p) {
      const int dd = r + p * 16;
      float4 v = *(const float4*)(x + (size_t)b * D_ * T_ + (size_t)(dc + dd) * T_ + t0 + cf * 4);
      xrow[(cf * 4 + 0) * 257 + dc + dd] = v.x;
      xrow[(cf * 4 + 1) * 257 + dc + dd] = v.y;
      xrow[(cf * 4 + 2) * 257 + dc + dd] = v.z;
      xrow[(cf * 4 + 3) * 257 + dc + dd] = v.w;
    }
  }
  __syncthreads();
  const int row = tid & 63;
  const int n = blk * 64 + row;
  const int c0 = tid >> 6;
  const int nc = min(cnt[n], CAND_MAX);
  for (int c = c0; c < nc; c += 4)
    atomicMin(&sbits[row], (unsigned)cand[(size_t)n * CAND_MAX + c].y);
  __syncthreads();
  const float th = __uint_as_float(sbits[row]) + EPS2;
  const float xq = xsq[n];
  for (int c = c0; c < nc; c += 4) {
    const int2 e = cand[(size_t)n * CAND_MAX + c];
    if (__int_as_float(e.y) <= th) {
      const float* wr = w + (size_t)e.x * D_;
      float acc = 0.f;
#pragma unroll 8
      for (int d = 0; d < D_; ++d) acc = fmaf(xrow[row * 257 + d], wr[d], acc);
      const float s = (xq + wsq[e.x]) - 2.0f * acc;   // bitwise == round-1 score
      atomicMin(&fin[row], ((unsigned long long)__float_as_uint(s) << 32) | (unsigned)e.x);
    }
  }
  __syncthreads();
  if (tid < 64) {
    const int idx = (int)(fin[tid] & 0xffffffffULL);
    sidx[tid] = idx;
    out_idx[blk * 64 + tid] = (float)idx;
    atomicAdd(&counts[idx], 1);
  }
  __syncthreads();
  // emit phase: out0[t][d] = x + (w[idx] - x), loss partial
  const int dx = tid & 15;
  const int tg = tid >> 4;
  float lsum = 0.f;
  for (int dc = 0; dc < D_; dc += 64) {
#pragma unroll
    for (int q = 0; q < 4; ++q) {
      const int t = q * 16 + tg;
      const int idx = sidx[t];
      const float4 wv = *(const float4*)(w + (size_t)idx * D_ + dc + dx * 4);
      const float x0 = xrow[t * 257 + dc + dx * 4 + 0];
      const float x1 = xrow[t * 257 + dc + dx * 4 + 1];
      const float x2 = xrow[t * 257 + dc + dx * 4 + 2];
      const float x3 = xrow[t * 257 + dc + dx * 4 + 3];
      const float d0 = wv.x - x0, d1 = wv.y - x1, d2 = wv.z - x2, d3 = wv.w - x3;
      float4 ov = make_float4(x0 + d0, x1 + d1, x2 + d2, x3 + d3);
      *(float4*)(out0 + (size_t)(blk * 64 + t) * D_ + dc + dx * 4) = ov;
      lsum += d0 * d0 + d1 * d1 + d2 * d2 + d3 * d3;
    }
  }
  for (int off = 32; off; off >>= 1) lsum += __shfl_down(lsum, off);
  if ((tid & 63) == 0) sred[tid >> 6] = lsum;
  __syncthreads();
  if (tid == 0) atomicAdd(sumsq, sred[0] + sred[1] + sred[2] + sred[3]);
}

// ---------------- loss + perplexity ----------------
__global__ void k_final(const int* __restrict__ counts, const float* __restrict__ sumsq,
                        float* __restrict__ out_scalars) {
  __shared__ float sred[4];
  const int tid = threadIdx.x;
  float s = 0.f;
  for (int k = tid; k < K_; k += 256) {
    const float p = (float)counts[k] / (float)N_;
    s += p * logf(p + 1e-10f);
  }
  for (int off = 32; off; off >>= 1) s += __shfl_down(s, off);
  if ((tid & 63) == 0) sred[tid >> 6] = s;
  __syncthreads();
  if (tid == 0) {
    const float ent = sred[0] + sred[1] + sred[2] + sred[3];
    const float m = sumsq[0] / 16777216.0f;
    out_scalars[0] = m + 0.25f * m;
    out_scalars[1] = expf(-ent);
  }
}

// ================= round-1 fallback path (used only if ws too small) =================
__global__ void k_wt(const float* __restrict__ w, float* __restrict__ wt) {
  __shared__ float tile[64][65];
  const int k0 = blockIdx.x * 64, d0 = blockIdx.y * 64;
  const int c = threadIdx.x & 15, r = threadIdx.x >> 4;
#pragma unroll
  for (int p = 0; p < 4; ++p) {
    const int kk = r + p * 16;
    float4 v = *(const float4*)(w + (size_t)(k0 + kk) * D_ + d0 + c * 4);
    tile[kk][c * 4 + 0] = v.x; tile[kk][c * 4 + 1] = v.y;
    tile[kk][c * 4 + 2] = v.z; tile[kk][c * 4 + 3] = v.w;
  }
  __syncthreads();
#pragma unroll
  for (int p = 0; p < 4; ++p) {
    const int dd = r + p * 16;
    float4 v = make_float4(tile[c * 4 + 0][dd], tile[c * 4 + 1][dd],
                           tile[c * 4 + 2][dd], tile[c * 4 + 3][dd]);
    *(float4*)(wt + (size_t)(d0 + dd) * K_ + k0 + c * 4) = v;
  }
}

__launch_bounds__(256, 4)
__global__ void k_argmin(const float* __restrict__ x, const float* __restrict__ wt,
                         const float* __restrict__ xsq, const float* __restrict__ wsq,
                         unsigned long long* __restrict__ packed) {
  extern __shared__ char smem[];
  float* Xs = (float*)smem;
  float* Ws = (float*)(smem + 32 * 128 * sizeof(float));
  const int tid = threadIdx.x;
  const int tx = tid & 15, ty = tid >> 4;
  const int n0 = blockIdx.x * 128, k0 = blockIdx.y * 128;
  const int b = n0 >> 12, t0 = n0 & (T_ - 1);
  const float* xbase = x + (size_t)b * D_ * T_ + t0;
  const float* wbase = wt + k0;
  float acc[8][8];
#pragma unroll
  for (int i = 0; i < 8; ++i)
#pragma unroll
    for (int j = 0; j < 8; ++j) acc[i][j] = 0.f;
  const int sr = tid >> 5, sc = tid & 31;
  for (int dc = 0; dc < D_; dc += 32) {
#pragma unroll
    for (int p = 0; p < 4; ++p) {
      const int rr = sr + p * 8;
      const float4 xv = *(const float4*)(xbase + (size_t)(dc + rr) * T_ + sc * 4);
      *(float4*)(Xs + rr * 128 + sc * 4) = xv;
      const float4 wv = *(const float4*)(wbase + (size_t)(dc + rr) * K_ + sc * 4);
      *(float4*)(Ws + rr * 128 + sc * 4) = wv;
    }
    __syncthreads();
#pragma unroll 4
    for (int d = 0; d < 32; ++d) {
      const float4 xa = *(const float4*)(Xs + d * 128 + tx * 8);
      const float4 xb = *(const float4*)(Xs + d * 128 + tx * 8 + 4);
      const float4 wa = *(const float4*)(Ws + d * 128 + ty * 8);
      const float4 wb = *(const float4*)(Ws + d * 128 + ty * 8 + 4);
      const float xr[8] = {xa.x, xa.y, xa.z, xa.w, xb.x, xb.y, xb.z, xb.w};
      const float wr[8] = {wa.x, wa.y, wa.z, wa.w, wb.x, wb.y, wb.z, wb.w};
#pragma unroll
      for (int i = 0; i < 8; ++i)
#pragma unroll
        for (int j = 0; j < 8; ++j)
          acc[i][j] = fmaf(xr[i], wr[j], acc[i][j]);
    }
    __syncthreads();
  }
  float xq[8];
#pragma unroll
  for (int i = 0; i < 8; ++i) xq[i] = xsq[n0 + tx * 8 + i];
  float best[8]; int bidx[8];
#pragma unroll
  for (int i = 0; i < 8; ++i) { best[i] = INFINITY; bidx[i] = 0; }
#pragma unroll
  for (int j = 0; j < 8; ++j) {
    const int kk = k0 + ty * 8 + j;
    const float wq = wsq[kk];
#pragma unroll
    for (int i = 0; i < 8; ++i) {
      const float s = (xq[i] + wq) - 2.0f * acc[i][j];
      if (s < best[i]) { best[i] = s; bidx[i] = kk; }
    }
  }
  float* rv = (float*)smem;
  int* ri = (int*)(smem + 16 * 128 * sizeof(float));
#pragma unroll
  for (int i = 0; i < 8; ++i) {
    rv[ty * 128 + tx * 8 + i] = best[i];
    ri[ty * 128 + tx * 8 + i] = bidx[i];
  }
  __syncthreads();
  if (tid < 128) {
    float bv = rv[tid]; int bi = ri[tid];
#pragma unroll
    for (int u = 1; u < 16; ++u) {
      const float v = rv[u * 128 + tid];
      const int ii = ri[u * 128 + tid];
      if (v < bv || (v == bv && ii < bi)) { bv = v; bi = ii; }
    }
    const unsigned long long pk =
        ((unsigned long long)__float_as_uint(bv) << 32) | (unsigned int)bi;
    atomicMin(packed + n0 + tid, pk);
  }
}

__global__ void k_unpack(const unsigned long long* __restrict__ p, int* __restrict__ fi) {
  const int i = blockIdx.x * 256 + threadIdx.x;
  fi[i] = (int)(p[i] & 0xffffffffULL);
}

__global__ void k_emit(const float* __restrict__ x, const float* __restrict__ w,
                       const int* __restrict__ fidx,
                       float* __restrict__ out0, float* __restrict__ out_idx,
                       int* __restrict__ counts, float* __restrict__ sumsq) {
  __shared__ float xs[64 * 65];
  __shared__ int sidx[64];
  __shared__ float sred[4];
  const int b = blockIdx.y, t0 = blockIdx.x * 64;
  const int tid = threadIdx.x;
  if (tid < 64) {
    const int n = b * T_ + t0 + tid;
    const int idx = fidx[n];
    sidx[tid] = idx;
    out_idx[n] = (float)idx;
    atomicAdd(&counts[idx], 1);
  }
  __syncthreads();
  const int r = tid >> 4;
  const int c = tid & 15;
  float lsum = 0.f;
  for (int dc = 0; dc < D_; dc += 64) {
#pragma unroll
    for (int p = 0; p < 4; ++p) {
      const int dd = r + p * 16;
      float4 v = *(const float4*)(x + (size_t)b * D_ * T_ + (size_t)(dc + dd) * T_ + t0 + c * 4);
      xs[(c * 4 + 0) * 65 + dd] = v.x;
      xs[(c * 4 + 1) * 65 + dd] = v.y;
      xs[(c * 4 + 2) * 65 + dd] = v.z;
      xs[(c * 4 + 3) * 65 + dd] = v.w;
    }
    __syncthreads();
    const int dx = tid & 15;
    const int tg = tid >> 4;
#pragma unroll
    for (int q = 0; q < 4; ++q) {
      const int t = q * 16 + tg;
      const int idx = sidx[t];
      const float4 wv = *(const float4*)(w + (size_t)idx * D_ + dc + dx * 4);
      const float x0 = xs[t * 65 + dx * 4 + 0];
      const float x1 = xs[t * 65 + dx * 4 + 1];
      const float x2 = xs[t * 65 + dx * 4 + 2];
      const float x3 = xs[t * 65 + dx * 4 + 3];
      const float d0 = wv.x - x0, d1 = wv.y - x1, d2 = wv.z - x2, d3 = wv.w - x3;
      float4 ov = make_float4(x0 + d0, x1 + d1, x2 + d2, x3 + d3);
      *(float4*)(out0 + (size_t)(b * T_ + t0 + t) * D_ + dc + dx * 4) = ov;
      lsum += d0 * d0 + d1 * d1 + d2 * d2 + d3 * d3;
    }
    __syncthreads();
  }
  for (int off = 32; off; off >>= 1) lsum += __shfl_down(lsum, off);
  if ((tid & 63) == 0) sred[tid >> 6] = lsum;
  __syncthreads();
  if (tid == 0) atomicAdd(sumsq, sred[0] + sred[1] + sred[2] + sred[3]);
}

// =====================================================================================
extern "C" void kernel_launch(void* const* d_in, const int* in_sizes, int n_in,
                              void* d_out, int out_size, void* d_ws, size_t ws_size,
                              hipStream_t stream) {
  const float* x = (const float*)d_in[0];   // [16,256,4096]
  const float* w = (const float*)d_in[1];   // [1024,256]
  float* out = (float*)d_out;
  float* out0 = out;                    // [B,T,D]
  float* out_scalars = out + 16777216;  // loss, perplexity
  float* out_idx = out + 16777218;      // [N,1] as float

  char* ws = (char*)d_ws;
  const size_t NEED = 48u * 1024u * 1024u;

  if (ws_size >= NEED) {
    // ---- MFMA path ----
    unsigned short* xh = (unsigned short*)ws;                       // 32 MB
    unsigned short* wh = (unsigned short*)(ws + 33554432);          // 512 KB
    float* xsq = (float*)(ws + 34078720);                           // 256 KB
    float* wsq = (float*)(ws + 34340864);                           // 4 KB
    int* cnt = (int*)(ws + 34344960);                               // 256 KB
    int2* cand = (int2*)(ws + 34607104);                            // 12 MB
    int* counts = (int*)(ws + 47452160);                            // 4 KB
    float* sumsq = (float*)(ws + 47456256);

    hipMemsetAsync(cnt, 0, 262144, stream);
    hipMemsetAsync(counts, 0, 4096 + 256, stream);   // counts + sumsq

    k_prep<<<dim3(T_ / 64, B_), dim3(256), 0, stream>>>(x, xh, xsq);
    k_wsplit<<<dim3((K_ * D_) / 256), dim3(256), 0, stream>>>(w, wh);
    k_wsq<<<dim3(K_ / 256), dim3(256), 0, stream>>>(w, wsq);
    k_mfma<<<dim3(N_ / 256, 2), dim3(256), 0, stream>>>(xh, wh, xsq, wsq, cnt, cand);
    k_resc_emit<<<dim3(N_ / 64), dim3(256), 0, stream>>>(x, w, xsq, wsq, cnt, cand,
                                                         out0, out_idx, counts, sumsq);
    k_final<<<1, 256, 0, stream>>>(counts, sumsq, out_scalars);
  } else {
    // ---- round-1 fallback path ----
    unsigned long long* packed = (unsigned long long*)ws;            // 512 KB
    int* counts = (int*)(ws + 524288);                               // 4 KB
    float* sumsq = (float*)(ws + 528384);
    float* wsq = (float*)(ws + 528640);                              // 4 KB
    float* xsq = (float*)(ws + 532736);                              // 256 KB
    float* wt = (float*)(ws + 794880);                               // 1 MB
    int* final_idx = (int*)(ws + 1843200);                           // 256 KB

    hipMemsetAsync(packed, 0xFF, 524288, stream);
    hipMemsetAsync(counts, 0, 4096 + 256, stream);

    k_wt<<<dim3(K_ / 64, D_ / 64), dim3(256), 0, stream>>>(w, wt);
    k_wsq<<<dim3(K_ / 256), dim3(256), 0, stream>>>(w, wsq);
    k_xsq<<<dim3(T_ / 256, B_), dim3(256), 0, stream>>>(x, xsq);
    k_argmin<<<dim3(N_ / 128, K_ / 128), dim3(256), 32 * 1024, stream>>>(x, wt, xsq, wsq, packed);
    k_unpack<<<dim3(N_ / 256), dim3(256), 0, stream>>>(packed, final_idx);
    k_emit<<<dim3(T_ / 64, B_), dim3(256), 0, stream>>>(x, w, final_idx, out0, out_idx, counts, sumsq);
    k_final<<<1, 256, 0, stream>>>(counts, sumsq, out_scalars);
  }
}